// Round 8
// baseline (638.957 us; speedup 1.0000x reference)
//
#include <hip/hip_runtime.h>
#include <cmath>

// QuanvolutionSelfAttentionClassifier on MI355X — round 8.
//
// Algebra (verified R1/R2/R3/R5/R6/R7): softmax over length-1 axis == 1 ->
// attn_weights == mean_embeds (rotation/entangle params dead). With
// l = c*196 + p, embedding index d = p & 3; for input pixel (r,cc):
// d = (2*((r>>1)&1) + (cc>>1)) & 3.
//   logits[j] = lin_b[j] + sum_d M[d] * (cst[d][j] + T[d][j])
//   M[d]    = a + sum_pix x[pix]*gm(pix),   a = sum_c conv_b[c]/4
//   T[d][j] = sum_{pix: d(pix)==d} x[pix] * G[pix][j]
//
// R7 solved the spill (waves_per_eu(2,2): WRITE 85MB->1.3MB) but remained
// latency-bound (VALUBusy 20%, HBM 9%): parity split idles half the waves,
// 28 block barriers serialize, readlane chains + sched_barrier fences stall.
// v8: wave-PRIVATE design. Each wave owns 16 samples; lane = sample*4 +
// colgroup; colgroup cg accumulates T[d][3cg..3cg+2] (cg3: {T[d][9], mu[d]})
// -> acc[4][3]=12 regs. x transposed through per-wave private LDS planes
// (3x[16][36]) -> NO block barriers in the main loop (same-wave LDS pipe is
// in-order; R2-verified WAR idiom). G staged once to LDS as [pix][4][4]:
// per pixel ONE ds_read_b128 at 4 distinct addrs/wave (banks 0-15, 16-lane
// broadcast, conflict-free) + 3 fmac. M/logsoftmax reduce via quad __shfl.
// One __syncthreads total (after G staging).

#define GS_STRIDE 3136   // floats per ws G-slice (784*4)
#define WS_A      12544
#define WS_CST    12545  // 40 floats

__global__ void qsac_prep(const float* __restrict__ cw, const float* __restrict__ cb,
                          const float* __restrict__ lw, float* __restrict__ ws) {
  const int t = blockIdx.x * 98 + threadIdx.x;  // 8 x 98 = 784 pixels
  const int r = t / 28, cc = t - r * 28;
  const int kh = r & 1, kw = cc & 1;
  const int p = (r >> 1) * 14 + (cc >> 1);
  const float w0 = cw[(kh << 1) + kw],     w1 = cw[4 + (kh << 1) + kw],
              w2 = cw[8 + (kh << 1) + kw], w3 = cw[12 + (kh << 1) + kw];
  float g[10];
#pragma unroll
  for (int j = 0; j < 10; ++j)
    g[j] = w0 * lw[j * 784 + p]       + w1 * lw[j * 784 + 196 + p] +
           w2 * lw[j * 784 + 392 + p] + w3 * lw[j * 784 + 588 + p];
  const float gm = (w0 + w1 + w2 + w3) * (1.0f / 196.0f);
  float* d0 = ws + 0 * GS_STRIDE + t * 4;
  d0[0] = g[0]; d0[1] = g[1]; d0[2] = g[2]; d0[3] = 0.f;
  float* d1 = ws + 1 * GS_STRIDE + t * 4;
  d1[0] = g[3]; d1[1] = g[4]; d1[2] = g[5]; d1[3] = 0.f;
  float* d2 = ws + 2 * GS_STRIDE + t * 4;
  d2[0] = g[6]; d2[1] = g[7]; d2[2] = g[8]; d2[3] = 0.f;
  float* d3 = ws + 3 * GS_STRIDE + t * 4;
  d3[0] = g[9]; d3[1] = gm;   d3[2] = 0.f;  d3[3] = 0.f;

  if (blockIdx.x == 0) {
    const int u = threadIdx.x;
    if (u < 40) {
      const int d = u / 10, j = u - (u / 10) * 10;
      const float b0 = cb[0], b1 = cb[1], b2 = cb[2], b3 = cb[3];
      float s = 0.f;
#pragma unroll 7
      for (int q = d; q < 196; q += 4)
        s += b0 * lw[j * 784 + q]       + b1 * lw[j * 784 + 196 + q] +
             b2 * lw[j * 784 + 392 + q] + b3 * lw[j * 784 + 588 + q];
      ws[WS_CST + u] = s;
    } else if (u == 40) {
      ws[WS_A] = (cb[0] + cb[1] + cb[2] + cb[3]) * 0.25f;
    }
  }
}

#define G_FLOATS 12544   // G in LDS: [784 pix][4 slices][4 floats]
#define PLANE_F  576     // one x-plane: [16 samples][36]
#define WPLANES  1728    // 3 planes per wave

// One pixel CC of row r_: 1 broadcast-ish ds_read_b128 + 3 fmac, static acc.
#define PIXD(CC, PAR)                                                         \
  {                                                                           \
    constexpr int DD = (2 * (PAR) + ((CC) >> 1)) & 3;                         \
    const float4 g = *reinterpret_cast<const float4*>(gp + (CC)*16);          \
    const float xv = (((CC)&3) == 0) ? trs[(CC)>>2].x                         \
                   : (((CC)&3) == 1) ? trs[(CC)>>2].y                         \
                   : (((CC)&3) == 2) ? trs[(CC)>>2].z : trs[(CC)>>2].w;       \
    acc[DD][0] += xv * g.x;                                                   \
    acc[DD][1] += xv * g.y;                                                   \
    acc[DD][2] += xv * g.z;                                                   \
  }

// Compute row r_ (plane S%3). PAR = ((S)>>1)&1 is valid because row bases
// (0, 12, 24) are all even and multiples of 3-periodicity is handled by S.
#define ROWC(S, RVAR)                                                         \
  {                                                                           \
    const float* rp = pl + ((S) % 3) * PLANE_F + sq36;                        \
    float4 trs[7];                                                            \
    _Pragma("unroll") for (int mm = 0; mm < 7; ++mm)                          \
      trs[mm] = *reinterpret_cast<const float4*>(rp + mm * 4);                \
    const float* gp = gbase + (RVAR) * 448;                                   \
    PIXD(0,  ((S)>>1)&1) PIXD(1,  ((S)>>1)&1) PIXD(2,  ((S)>>1)&1)            \
    PIXD(3,  ((S)>>1)&1) PIXD(4,  ((S)>>1)&1) PIXD(5,  ((S)>>1)&1)            \
    PIXD(6,  ((S)>>1)&1) PIXD(7,  ((S)>>1)&1) PIXD(8,  ((S)>>1)&1)            \
    PIXD(9,  ((S)>>1)&1) PIXD(10, ((S)>>1)&1) PIXD(11, ((S)>>1)&1)            \
    PIXD(12, ((S)>>1)&1) PIXD(13, ((S)>>1)&1) PIXD(14, ((S)>>1)&1)            \
    PIXD(15, ((S)>>1)&1) PIXD(16, ((S)>>1)&1) PIXD(17, ((S)>>1)&1)            \
    PIXD(18, ((S)>>1)&1) PIXD(19, ((S)>>1)&1) PIXD(20, ((S)>>1)&1)            \
    PIXD(21, ((S)>>1)&1) PIXD(22, ((S)>>1)&1) PIXD(23, ((S)>>1)&1)            \
    PIXD(24, ((S)>>1)&1) PIXD(25, ((S)>>1)&1) PIXD(26, ((S)>>1)&1)            \
    PIXD(27, ((S)>>1)&1)                                                      \
  }

// Loop step S (r_ = RB+S, RB in {0,12}): write row r_+2 (slot (S+2)%3) into
// plane (S+2)%3 (its last read was row r_-1 at step S-1, earlier in program
// order -> same-wave in-order LDS pipe makes the WAR safe), reload that R
// slot with row min(r_+5,27), compute row r_.
#define STEPL(S)                                                              \
  {                                                                           \
    const int r_ = RB + (S);                                                  \
    float* wp = pl + (((S) + 2) % 3) * PLANE_F;                               \
    *reinterpret_cast<float4*>(wp + wadr1) = Ra[((S) + 2) % 3];               \
    if (lane < 48) *reinterpret_cast<float4*>(wp + wadr2) = Rb[((S) + 2) % 3];\
    const int rld = (r_ + 5 < 28) ? r_ + 5 : 27;                              \
    Ra[((S) + 2) % 3] = *reinterpret_cast<const float4*>(xg1 + rld * 28);     \
    if (lane < 48)                                                            \
      Rb[((S) + 2) % 3] = *reinterpret_cast<const float4*>(xg2 + rld * 28);   \
    ROWC(S, r_)                                                               \
    __builtin_amdgcn_wave_barrier();                                          \
  }

// Tail step (rows 24..27): stage only while rows remain, no loads.
#define STEPT(S)                                                              \
  {                                                                           \
    constexpr int r_ = 24 + (S);                                              \
    if constexpr ((S) < 2) {                                                  \
      float* wp = pl + (((S) + 2) % 3) * PLANE_F;                             \
      *reinterpret_cast<float4*>(wp + wadr1) = Ra[((S) + 2) % 3];             \
      if (lane < 48)                                                          \
        *reinterpret_cast<float4*>(wp + wadr2) = Rb[((S) + 2) % 3];           \
    }                                                                         \
    ROWC(S, r_)                                                               \
    __builtin_amdgcn_wave_barrier();                                          \
  }

__global__ __launch_bounds__(256)
__attribute__((amdgpu_waves_per_eu(2, 2))) void qsac_main(
    const float* __restrict__ x, const float* __restrict__ ws,
    const float* __restrict__ lin_b, float* __restrict__ out) {
  // [0,12544): G [784][4][4]; [12544,19456): 4 waves x 3 planes [16][36].
  __shared__ float smem[19456];  // 77824 B -> 2 blocks/CU

  const int tid = threadIdx.x;
  const int lane = tid & 63;
  const int wave = __builtin_amdgcn_readfirstlane(tid >> 6);
  const int cg = lane & 3;          // column group: j = 3*cg+q (cg3: j9 + mu)
  const int sq = lane >> 2;         // sample-in-wave 0..15
  const int sq36 = sq * 36;
  const int sbase = blockIdx.x * 64 + wave * 16;
  float* pl = smem + G_FLOATS + wave * WPLANES;
  const float* gbase = smem + cg * 4;

  // ---- G staging: 3136 float4 ws->LDS, interleaved [pix][slice] ----
  {
    const float4* gsrc = reinterpret_cast<const float4*>(ws);
    float4* gdst = reinterpret_cast<float4*>(smem);
#pragma unroll
    for (int k = 0; k < 12; ++k) {
      const int idx = tid + k * 256;
      gdst[idx] = gsrc[(idx & 3) * 784 + (idx >> 2)];
    }
    if (tid < 64) {
      const int idx = tid + 3072;
      gdst[idx] = gsrc[(idx & 3) * 784 + (idx >> 2)];
    }
  }

  // ---- x staging setup: wave-private. chunk c -> sample s=c/7, piece m=c%7.
  // c1 = lane (all 64), c2 = lane+64 (lane<48): 112 chunks = 16 samples/row.
  const int s1 = lane / 7, m1 = lane - s1 * 7;
  const int c2l = lane + 64;
  const int s2 = c2l / 7, m2 = c2l - s2 * 7;
  const float* xg1 = x + (size_t)(sbase + s1) * 784 + m1 * 4;
  const float* xg2 = x + (size_t)(sbase + ((lane < 48) ? s2 : 0)) * 784 + m2 * 4;
  const int wadr1 = s1 * 36 + m1 * 4;
  const int wadr2 = s2 * 36 + m2 * 4;

  // Prologue: rows 0,1 -> planes 0,1; rows 2,3,4 -> R slots 2,0,1.
  float4 Ra[3], Rb[3];
  float4 p0a = *reinterpret_cast<const float4*>(xg1);
  float4 p1a = *reinterpret_cast<const float4*>(xg1 + 28);
  float4 p0b, p1b;
  if (lane < 48) {
    p0b = *reinterpret_cast<const float4*>(xg2);
    p1b = *reinterpret_cast<const float4*>(xg2 + 28);
  }
  Ra[2] = *reinterpret_cast<const float4*>(xg1 + 2 * 28);
  Ra[0] = *reinterpret_cast<const float4*>(xg1 + 3 * 28);
  Ra[1] = *reinterpret_cast<const float4*>(xg1 + 4 * 28);
  if (lane < 48) {
    Rb[2] = *reinterpret_cast<const float4*>(xg2 + 2 * 28);
    Rb[0] = *reinterpret_cast<const float4*>(xg2 + 3 * 28);
    Rb[1] = *reinterpret_cast<const float4*>(xg2 + 4 * 28);
  }
  *reinterpret_cast<float4*>(pl + 0 * PLANE_F + wadr1) = p0a;
  *reinterpret_cast<float4*>(pl + 1 * PLANE_F + wadr1) = p1a;
  if (lane < 48) {
    *reinterpret_cast<float4*>(pl + 0 * PLANE_F + wadr2) = p0b;
    *reinterpret_cast<float4*>(pl + 1 * PLANE_F + wadr2) = p1b;
  }
  __syncthreads();  // G visibility across waves (x planes are private)

  float acc[4][3];
#pragma unroll
  for (int d = 0; d < 4; ++d)
#pragma unroll
    for (int q = 0; q < 3; ++q) acc[d][q] = 0.f;

  // ---- main loop: rows 0..23 in two 12-step groups, rows 24..27 peeled.
  // Plane index S%3 and d-parity (S>>1)&1 are S-static (RB in {0,12}).
#pragma unroll 1
  for (int it = 0; it < 2; ++it) {
    const int RB = it * 12;
    STEPL(0)  STEPL(1)  STEPL(2)  STEPL(3)  STEPL(4)  STEPL(5)
    STEPL(6)  STEPL(7)  STEPL(8)  STEPL(9)  STEPL(10) STEPL(11)
  }
  STEPT(0) STEPT(1) STEPT(2) STEPT(3)

  // ---- epilogue: all quad-local (shfl), no barriers ----
  const float a = ws[WS_A];
  float M[4];
#pragma unroll
  for (int d = 0; d < 4; ++d) {
    const float mval = a + acc[d][1];                   // valid on cg3 lanes
    M[d] = __shfl(mval, (lane & ~3) | 3);               // broadcast from cg3
  }
  float v[3];
#pragma unroll
  for (int q = 0; q < 3; ++q) {
    const int j = 3 * cg + q;
    const int jj = (j > 9) ? 9 : j;                     // clamp (cg3 q1,q2 unused)
    float t = lin_b[jj];
#pragma unroll
    for (int d = 0; d < 4; ++d)
      t += M[d] * (ws[WS_CST + d * 10 + jj] + acc[d][q]);
    v[q] = t;
  }
  const bool full = (cg < 3);
  float mx = full ? fmaxf(fmaxf(v[0], v[1]), v[2]) : v[0];
  mx = fmaxf(mx, __shfl_xor(mx, 1));
  mx = fmaxf(mx, __shfl_xor(mx, 2));
  float se = __expf(v[0] - mx) +
             (full ? (__expf(v[1] - mx) + __expf(v[2] - mx)) : 0.f);
  se += __shfl_xor(se, 1);
  se += __shfl_xor(se, 2);
  const float lse = mx + __logf(se);

  float* op = out + (size_t)(sbase + sq) * 10;
  op[3 * cg] = v[0] - lse;                              // cg3 -> j9
  if (full) {
    op[3 * cg + 1] = v[1] - lse;
    op[3 * cg + 2] = v[2] - lse;
  }
}

extern "C" void kernel_launch(void* const* d_in, const int* in_sizes, int n_in,
                              void* d_out, int out_size, void* d_ws, size_t ws_size,
                              hipStream_t stream) {
  (void)n_in; (void)ws_size; (void)out_size;
  const float* x = (const float*)d_in[0];
  const float* conv_w = (const float*)d_in[1];
  const float* conv_b = (const float*)d_in[2];
  // d_in[3]/d_in[4] (rotation/entangle) are dead: softmax over length-1 == 1.
  const float* lin_w = (const float*)d_in[5];
  const float* lin_b = (const float*)d_in[6];
  float* out = (float*)d_out;
  float* ws = (float*)d_ws;

  hipLaunchKernelGGL(qsac_prep, dim3(8), dim3(98), 0, stream,
                     conv_w, conv_b, lin_w, ws);

  const int B = in_sizes[0] / 784;  // 32768
  const int nblk = B / 64;          // 512 blocks x 256 threads
  hipLaunchKernelGGL(qsac_main, dim3(nblk), dim3(256), 0, stream,
                     x, ws, lin_b, out);
}

// Round 9
// 60.080 us; speedup vs baseline: 10.6351x; 10.6351x over previous
//
#include <hip/hip_runtime.h>
#include <cmath>

// QuanvolutionSelfAttentionClassifier on MI355X — round 9.
//
// Algebra (verified R1/R2/R3/R5/R6/R7/R8): softmax over length-1 axis == 1 ->
// attn_weights == mean_embeds (rotation/entangle params dead). With
// l = c*196 + p, embedding index d = p & 3; for input pixel (r,cc):
// d = (2*((r>>1)&1) + (cc>>1)) & 3.
//   logits[j] = lin_b[j] + sum_d M[d] * (cst[d][j] + T[d][j])
//   M[d]    = a + sum_pix x[pix]*gm(pix),   a = sum_c conv_b[c]/4
//   T[d][j] = sum_{pix: d(pix)==d} x[pix] * G[pix][j]
//
// v9 = R7 (74us, spill-free, verified) minus its two serializers:
//  (1) per-pair sched_barrier(0) fences removed — they forced 14 serialized
//      24-instr readlane->fmac clusters per step (VALUBusy 20%). The fences
//      were anti-spill paranoia; waves_per_eu(2,2) already fixed the spill.
//  (2) row-parity compute split -> PAIR split: all 4 waves compute every row
//      (wave rh takes pairs 0-6 / 7-13; DD stays compile-time; the existing
//      rh-reduction in the epilogue sums the partial T/mu). Per-step critical
//      path halves and no wave idles.
// G prefetch: every step, temp + writeback (Gt <- row r+2; use Gb[S&1];
// Gb[S&1] = Gt) — 2-step latency cover. Everything else is R7 byte-identical.

#define WS_A    9408
#define WS_CST  9409

__global__ void qsac_prep(const float* __restrict__ cw, const float* __restrict__ cb,
                          const float* __restrict__ lw, float* __restrict__ ws) {
  const int t = blockIdx.x * 98 + threadIdx.x;  // 8 x 98 = 784 pixels
  const int r = t / 28, cc = t - r * 28;
  const int kh = r & 1, kw = cc & 1;
  const int p = (r >> 1) * 14 + (cc >> 1);
  const float w0 = cw[(kh << 1) + kw],     w1 = cw[4 + (kh << 1) + kw],
              w2 = cw[8 + (kh << 1) + kw], w3 = cw[12 + (kh << 1) + kw];
  float g[10];
#pragma unroll
  for (int j = 0; j < 10; ++j)
    g[j] = w0 * lw[j * 784 + p]       + w1 * lw[j * 784 + 196 + p] +
           w2 * lw[j * 784 + 392 + p] + w3 * lw[j * 784 + 588 + p];
  const float gm = (w0 + w1 + w2 + w3) * (1.0f / 196.0f);
  // Layout: ws[ch*4704 + r*168 + pr*12 + e*6 + k]; k<5 -> j=ch*5+k, k=5 -> 0|gm.
  const int pr = cc >> 1, e = cc & 1;
  float* d0 = ws + r * 168 + pr * 12 + e * 6;
  d0[0] = g[0]; d0[1] = g[1]; d0[2] = g[2]; d0[3] = g[3]; d0[4] = g[4]; d0[5] = 0.f;
  float* d1 = ws + 4704 + r * 168 + pr * 12 + e * 6;
  d1[0] = g[5]; d1[1] = g[6]; d1[2] = g[7]; d1[3] = g[8]; d1[4] = g[9]; d1[5] = gm;

  if (blockIdx.x == 0) {
    const int u = threadIdx.x;
    if (u < 40) {
      const int d = u / 10, j = u - (u / 10) * 10;
      const float b0 = cb[0], b1 = cb[1], b2 = cb[2], b3 = cb[3];
      float s = 0.f;
#pragma unroll 7
      for (int q = d; q < 196; q += 4)
        s += b0 * lw[j * 784 + q]       + b1 * lw[j * 784 + 196 + q] +
             b2 * lw[j * 784 + 392 + q] + b3 * lw[j * 784 + 588 + q];
      ws[WS_CST + u] = s;
    } else if (u == 40) {
      ws[WS_A] = (cb[0] + cb[1] + cb[2] + cb[3]) * 0.25f;
    }
  }
}

#define BAR()                                            \
  asm volatile("s_waitcnt lgkmcnt(0)" ::: "memory");     \
  __builtin_amdgcn_s_barrier();                          \
  asm volatile("" ::: "memory");

// Broadcast float I of the wave's G row (held as per-lane float4 over lanes
// 0..41) into an SGPR: compile-time component select + v_readlane.
template <int I>
__device__ __forceinline__ float rl(const float4& v) {
  constexpr int c = I & 3;
  const float f = (c == 0) ? v.x : (c == 1) ? v.y : (c == 2) ? v.z : v.w;
  return __int_as_float(__builtin_amdgcn_readlane(__float_as_int(f), I >> 2));
}

// One pixel-pair P (cols 2P,2P+1; shared d-class): 12 readlane + 12 fmac.
// NO fence — let the scheduler interleave pairs.
#define PAIRR(P, PAR, GB)                                                     \
  {                                                                           \
    constexpr int DD = (2 * (PAR) + ((P)&3)) & 3;                             \
    const float xA = ((P)&1) ? tr[(P) >> 1].z : tr[(P) >> 1].x;               \
    const float xB = ((P)&1) ? tr[(P) >> 1].w : tr[(P) >> 1].y;               \
    acc[DD][0] += xA * rl<12 * (P) + 0>(GB);                                  \
    acc[DD][1] += xA * rl<12 * (P) + 1>(GB);                                  \
    acc[DD][2] += xA * rl<12 * (P) + 2>(GB);                                  \
    acc[DD][3] += xA * rl<12 * (P) + 3>(GB);                                  \
    acc[DD][4] += xA * rl<12 * (P) + 4>(GB);                                  \
    acc[DD][5] += xA * rl<12 * (P) + 5>(GB);                                  \
    acc[DD][0] += xB * rl<12 * (P) + 6>(GB);                                  \
    acc[DD][1] += xB * rl<12 * (P) + 7>(GB);                                  \
    acc[DD][2] += xB * rl<12 * (P) + 8>(GB);                                  \
    acc[DD][3] += xB * rl<12 * (P) + 9>(GB);                                  \
    acc[DD][4] += xB * rl<12 * (P) + 10>(GB);                                 \
    acc[DD][5] += xB * rl<12 * (P) + 11>(GB);                                 \
  }

// Compute row r_ at step S: ALL waves participate; wave rh takes pairs 0-6
// or 7-13. G for row r_+2 prefetched into Gt, written back after use.
#define COMPUTE(S, GCUR)                                                      \
  {                                                                           \
    const int rnx = (r_ + 2 < 28) ? r_ + 2 : 27;                              \
    const float4 Gt = *reinterpret_cast<const float4*>(gsl + rnx * 168);      \
    const float* rp = smem + ((S)&3) * 2304 + lane36;                         \
    float4 tr[7];                                                             \
    _Pragma("unroll") for (int mm = 0; mm < 7; ++mm)                          \
      tr[mm] = *reinterpret_cast<const float4*>(rp + mm * 4);                 \
    if (rh == 0) {                                                            \
      PAIRR(0, ((S) >> 1) & 1, GCUR) PAIRR(1, ((S) >> 1) & 1, GCUR)           \
      PAIRR(2, ((S) >> 1) & 1, GCUR) PAIRR(3, ((S) >> 1) & 1, GCUR)           \
      PAIRR(4, ((S) >> 1) & 1, GCUR) PAIRR(5, ((S) >> 1) & 1, GCUR)           \
      PAIRR(6, ((S) >> 1) & 1, GCUR)                                          \
    } else {                                                                  \
      PAIRR(7, ((S) >> 1) & 1, GCUR) PAIRR(8, ((S) >> 1) & 1, GCUR)           \
      PAIRR(9, ((S) >> 1) & 1, GCUR) PAIRR(10, ((S) >> 1) & 1, GCUR)          \
      PAIRR(11, ((S) >> 1) & 1, GCUR) PAIRR(12, ((S) >> 1) & 1, GCUR)         \
      PAIRR(13, ((S) >> 1) & 1, GCUR)                                         \
    }                                                                         \
    GCUR = Gt;                                                                \
  }

// Step S (0..3): row r_ = rb+S (plane r_%4 == S). Stage row r_+3 into plane
// (S+3)&3 (last read at step S-1, protected by that step's barrier), reload
// its R-slot with row r_+7. All waves compute. lgkmcnt(0)-only drain + raw
// barrier keeps global prefetch (vmcnt) in flight.
#define STEP(S, GCUR)                                                         \
  {                                                                           \
    const int r_ = rb + (S);                                                  \
    if (r_ + 3 < 28) {                                                        \
      float* wp = smem + (((S) + 3) & 3) * 2304;                              \
      *reinterpret_cast<float4*>(wp + wadr1) = R1[((S) + 3) & 3];             \
      if (has2) *reinterpret_cast<float4*>(wp + wadr2) = R2[((S) + 3) & 3];   \
      if (r_ + 7 < 28) {                                                      \
        R1[((S) + 3) & 3] =                                                   \
            *reinterpret_cast<const float4*>(xg1 + (r_ + 7) * 28);            \
        if (has2)                                                             \
          R2[((S) + 3) & 3] =                                                 \
              *reinterpret_cast<const float4*>(xg2 + (r_ + 7) * 28);          \
      }                                                                       \
    }                                                                         \
    COMPUTE(S, GCUR)                                                          \
    BAR()                                                                     \
  }

__global__ __launch_bounds__(256)
__attribute__((amdgpu_waves_per_eu(2, 2))) void qsac_main(
    const float* __restrict__ x, const float* __restrict__ ws,
    const float* __restrict__ lin_b, float* __restrict__ out) {
  __shared__ float smem[4 * 2304];  // 36.9 KB: 4 x-planes [64][36]

  const int tid = threadIdx.x;
  const int lane = tid & 63;
  const int wid = __builtin_amdgcn_readfirstlane(tid >> 6);
  const int ch = wid >> 1, rh = wid & 1;
  const int sbase = blockIdx.x * 64;
  const int lane36 = lane * 36;
  // Per-lane G slice pointer: lane l<42 covers floats [4l,4l+4) of each
  // 168-float row of this wave's ch slice (lanes >=42 clamp to 0, unused).
  const float* gsl = ws + ch * 4704 + ((lane < 42) ? lane * 4 : 0);

  // x staging: chunk c -> sample s=c/7, 16B-piece m=c%7. c1 = tid (all),
  // c2 = tid+256 (tid<192; wave-uniform since 192 = 3*64). 448 chunks/row.
  const int s1 = tid / 7, m1 = tid - s1 * 7;
  const bool has2 = tid < 192;
  const int c2 = tid + 256;
  const int s2 = c2 / 7, m2 = c2 - s2 * 7;
  const float* xg1 = x + (size_t)(sbase + s1) * 784 + m1 * 4;
  const float* xg2 = x + (size_t)(sbase + (has2 ? s2 : 0)) * 784 + m2 * 4;
  const int wadr1 = s1 * 36 + m1 * 4;
  const int wadr2 = s2 * 36 + m2 * 4;

  // G double-buffer: rows 0 and 1.
  float4 Gb0 = *reinterpret_cast<const float4*>(gsl + 0 * 168);
  float4 Gb1 = *reinterpret_cast<const float4*>(gsl + 1 * 168);

  // Prologue: rows 0-2 -> planes 0-2; rows 3-6 -> R*[3],R*[0],R*[1],R*[2].
  float4 R1[4], R2[4];
  float4 a0 = *reinterpret_cast<const float4*>(xg1);
  float4 a1 = *reinterpret_cast<const float4*>(xg1 + 28);
  float4 a2 = *reinterpret_cast<const float4*>(xg1 + 56);
  float4 b0, b1, b2;
  if (has2) {
    b0 = *reinterpret_cast<const float4*>(xg2);
    b1 = *reinterpret_cast<const float4*>(xg2 + 28);
    b2 = *reinterpret_cast<const float4*>(xg2 + 56);
  }
  R1[3] = *reinterpret_cast<const float4*>(xg1 + 3 * 28);
  R1[0] = *reinterpret_cast<const float4*>(xg1 + 4 * 28);
  R1[1] = *reinterpret_cast<const float4*>(xg1 + 5 * 28);
  R1[2] = *reinterpret_cast<const float4*>(xg1 + 6 * 28);
  if (has2) {
    R2[3] = *reinterpret_cast<const float4*>(xg2 + 3 * 28);
    R2[0] = *reinterpret_cast<const float4*>(xg2 + 4 * 28);
    R2[1] = *reinterpret_cast<const float4*>(xg2 + 5 * 28);
    R2[2] = *reinterpret_cast<const float4*>(xg2 + 6 * 28);
  }
  *reinterpret_cast<float4*>(smem + 0 * 2304 + wadr1) = a0;
  *reinterpret_cast<float4*>(smem + 1 * 2304 + wadr1) = a1;
  *reinterpret_cast<float4*>(smem + 2 * 2304 + wadr1) = a2;
  if (has2) {
    *reinterpret_cast<float4*>(smem + 0 * 2304 + wadr2) = b0;
    *reinterpret_cast<float4*>(smem + 1 * 2304 + wadr2) = b1;
    *reinterpret_cast<float4*>(smem + 2 * 2304 + wadr2) = b2;
  }
  BAR()

  float acc[4][6];
#pragma unroll
  for (int d = 0; d < 4; ++d)
#pragma unroll
    for (int q = 0; q < 6; ++q) acc[d][q] = 0.f;

  // All waves compute every row; Gb ping-pong by step parity.
#pragma unroll 1
  for (int it = 0; it < 7; ++it) {
    const int rb = it * 4;
    STEP(0, Gb0) STEP(1, Gb1) STEP(2, Gb0) STEP(3, Gb1)
  }

  // ---- epilogue (planes dead; overlay Red [0,3072) / Mld [3072,3328) /
  // L [3328,4096)). rh-reduction sums the pair-split partials. ----
  if (rh == 1) {
    float* rd = smem + ch * 1536 + lane * 24;
#pragma unroll
    for (int d = 0; d < 4; ++d)
#pragma unroll
      for (int q = 0; q < 6; ++q) rd[d * 6 + q] = acc[d][q];
  }
  __syncthreads();
  if (rh == 0) {
    const float* rd = smem + ch * 1536 + lane * 24;
#pragma unroll
    for (int d = 0; d < 4; ++d)
#pragma unroll
      for (int q = 0; q < 6; ++q) acc[d][q] += rd[d * 6 + q];
  }
  if (wid == 2) {  // ch1, rh0: full mean sums in slot 5 after reduction
    const float a = ws[WS_A];
#pragma unroll
    for (int d = 0; d < 4; ++d) smem[3072 + lane * 4 + d] = a + acc[d][5];
  }
  __syncthreads();
  if (rh == 0) {
    float M[4];
#pragma unroll
    for (int d = 0; d < 4; ++d) M[d] = smem[3072 + lane * 4 + d];
#pragma unroll
    for (int q = 0; q < 5; ++q) {
      const int j = ch * 5 + q;
      float v = lin_b[j];
#pragma unroll
      for (int d = 0; d < 4; ++d)
        v += M[d] * (ws[WS_CST + d * 10 + j] + acc[d][q]);
      smem[3328 + lane * 12 + j] = v;
    }
  }
  __syncthreads();
  if (wid == 0) {
    float logits[10];
#pragma unroll
    for (int j = 0; j < 10; ++j) logits[j] = smem[3328 + lane * 12 + j];
    float mx = logits[0];
#pragma unroll
    for (int j = 1; j < 10; ++j) mx = fmaxf(mx, logits[j]);
    float se = 0.f;
#pragma unroll
    for (int j = 0; j < 10; ++j) se += __expf(logits[j] - mx);
    const float lse = mx + __logf(se);
    float* op = out + (size_t)(sbase + lane) * 10;
#pragma unroll
    for (int j = 0; j < 10; ++j) op[j] = logits[j] - lse;
  }
}

extern "C" void kernel_launch(void* const* d_in, const int* in_sizes, int n_in,
                              void* d_out, int out_size, void* d_ws, size_t ws_size,
                              hipStream_t stream) {
  (void)n_in; (void)ws_size; (void)out_size;
  const float* x = (const float*)d_in[0];
  const float* conv_w = (const float*)d_in[1];
  const float* conv_b = (const float*)d_in[2];
  // d_in[3]/d_in[4] (rotation/entangle) are dead: softmax over length-1 == 1.
  const float* lin_w = (const float*)d_in[5];
  const float* lin_b = (const float*)d_in[6];
  float* out = (float*)d_out;
  float* ws = (float*)d_ws;

  hipLaunchKernelGGL(qsac_prep, dim3(8), dim3(98), 0, stream,
                     conv_w, conv_b, lin_w, ws);

  const int B = in_sizes[0] / 784;  // 32768
  const int nblk = B / 64;          // 512 blocks x 256 threads
  hipLaunchKernelGGL(qsac_main, dim3(nblk), dim3(256), 0, stream,
                     x, ws, lin_b, out);
}